// Round 9
// baseline (253.570 us; speedup 1.0000x reference)
//
#include <hip/hip_runtime.h>
#include <hip/hip_bf16.h>

#define VQ_D   64
#define VQ_K   1024
#define ROWS_PER_BLOCK 256           // 8 waves x 32 rows, 32x32x16 MFMA
#define EPS    0.02f                 // 0.015 bf16-split margin + 5-bit pack (<=32 ulp)

typedef __attribute__((ext_vector_type(8)))  short short8_t;
typedef __attribute__((ext_vector_type(4)))  float f32x4;
typedef __attribute__((ext_vector_type(16))) float f32x16;

static __device__ __forceinline__ short f2bf_s(float f) {
    __hip_bfloat16 b = __float2bfloat16(f);
    short s; __builtin_memcpy(&s, &b, 2); return s;
}
static __device__ __forceinline__ float bf2f(short s) {
    __hip_bfloat16 b; __builtin_memcpy(&b, &s, 2); return __bfloat162float(b);
}

// async 16B/lane global->LDS copy (gfx950). lds base wave-uniform; HW writes
// base + lane*16. Global src per-lane.
typedef const __attribute__((address_space(1))) unsigned int* gas_t;
typedef       __attribute__((address_space(3))) unsigned int* las_t;
static __device__ __forceinline__ void stage16(const void* g, void* l) {
    __builtin_amdgcn_global_load_lds((gas_t)g, (las_t)l, 16, 0, 0);
}

// ---------------- kernel 0: swizzle w into 32x32x16 B-fragment order + wsq
// Tile T = 64 codes (kt granule) = 8192 shorts = 16 sub-blocks of 1KB:
//   sub b = (half*4 + s)*2 + hl   (half = code>>5 in tile, s = dim>>4, hl hi/lo)
//   within sub: lane = col + 32*kg (col = code&31, kg = (dim>>3)&1), j = dim&7
//   -> B frag for v_mfma_f32_32x32x16_bf16: col = lane&31, k = (lane>>5)*8 + j.
// wsq fmaf chain is UNCHANGED from prior rounds (bit-identical fix contract).
__global__ __launch_bounds__(256) void vq_prep_kernel(
    const float* __restrict__ w, short* __restrict__ wS,
    float* __restrict__ wsq_g, float* __restrict__ wsqm_g,
    int* __restrict__ counter) {
    const int c = blockIdx.x * 256 + threadIdx.x;   // code id; grid = K/256
    if (c == 0) *counter = 0;
    if (c >= VQ_K) return;
    const int T = c >> 6, cc = c & 63, half = cc >> 5, col = cc & 31;
    short* tbase = wS + (size_t)T * 8192;
    float sx = 0.f, sy = 0.f, sz = 0.f, sw = 0.f;
#pragma unroll
    for (int b = 0; b < 2; ++b)
#pragma unroll
        for (int q = 0; q < 4; ++q) {
            const float* src = w + (size_t)c * VQ_D + b * 32 + q * 8;   // dims d0..d0+7
            f32x4 v0 = *reinterpret_cast<const f32x4*>(src);
            f32x4 v1 = *reinterpret_cast<const f32x4*>(src + 4);
            float vv[8] = {v0[0], v0[1], v0[2], v0[3], v1[0], v1[1], v1[2], v1[3]};
            short8_t hs, ls;
#pragma unroll
            for (int j = 0; j < 8; ++j) {
                short h = f2bf_s(vv[j]);
                hs[j] = h;
                ls[j] = f2bf_s(vv[j] - bf2f(h));
            }
            const int s  = b * 2 + (q >> 1);      // dim slice (16 dims)
            const int kg = q & 1;                 // k-group within slice
            const int base = ((half * 4 + s) * 2) * 512 + (col + 32 * kg) * 8;
            *reinterpret_cast<short8_t*>(tbase + base)       = hs;
            *reinterpret_cast<short8_t*>(tbase + base + 512) = ls;
            // wsq in EXACT round-2 partial order (f32x4 ascending, 4 chains)
            sx = fmaf(v0[0], v0[0], sx); sy = fmaf(v0[1], v0[1], sy);
            sz = fmaf(v0[2], v0[2], sz); sw = fmaf(v0[3], v0[3], sw);
            sx = fmaf(v1[0], v1[0], sx); sy = fmaf(v1[1], v1[1], sy);
            sz = fmaf(v1[2], v1[2], sz); sw = fmaf(v1[3], v1[3], sw);
        }
    float s = (sx + sy) + (sz + sw);
    wsq_g[c]  = s;            // exact, for fix kernel
    wsqm_g[c] = -0.5f * s;    // MFMA C-bias: argmax(dot - wsq/2) == argmin(wsq - 2dot)
}

// ---------------- kernel 1: 32x32x16-MFMA scores, 5-bit-packed top-2
// Per wave: 32 rows (row = wid*32 + lane&31), scans 64 codes/kt as 2
// half-tiles x 12-MFMA hi/lo chains (24 MFMA/kt vs 48 with 16x16x32 --
// +20% FLOP/cyc per m119, and half the issue slots / lgkmcnt points).
// C/D layout (m74/m101): col=lane&31, row=(reg&3)+8*(reg>>2)+4*(lane>>5).
// Pack: 5 bits (kt*2+half) -- lane's code column is lane-constant.
__global__ __launch_bounds__(512, 2) void vq_main_kernel(
    const float* __restrict__ x, const short* __restrict__ wS,
    const float* __restrict__ wsqm_g, const float* __restrict__ w,
    float* __restrict__ qout, float* __restrict__ iout,
    int* __restrict__ counter, int* __restrict__ list, int cap) {

    __shared__ short bS[2][8192];         // 32 KB: double-buffered 16KB kt-tile
    __shared__ float wsqm[VQ_K];          // 4 KB
    __shared__ int   idxL[ROWS_PER_BLOCK];
    __shared__ float gapL[ROWS_PER_BLOCK];

    const int t    = threadIdx.x;         // 0..511
    const int wid  = t >> 6;              // 0..7
    const int lane = t & 63;
    const int col  = lane & 31;
    const int kg   = lane >> 5;
    const long long rowBase = (long long)blockIdx.x * ROWS_PER_BLOCK;
    const int IMASK = (int)0xFFFFFFE0u;   // clears 5 pack bits

    // ---- stage wsqm (block-shared)
#pragma unroll
    for (int i = 0; i < 2; ++i) wsqm[i * 512 + t] = wsqm_g[i * 512 + t];

    // ---- prologue: async-stage kt=0 into buf 0 (wave w -> 1KB sub-blocks 2w,2w+1)
    {
        const short* g0 = wS + wid * 1024;
#pragma unroll
        for (int i = 0; i < 2; ++i)
            stage16(g0 + i * 512 + lane * 8, &bS[0][wid * 1024 + i * 512]);
    }

    // ---- A fragments from global x (hi/lo bf16 split)
    // A frag (32x16): row = lane&31, k = kg*8 + j; slice s covers dims 16s..16s+15
    short8_t ah[4], al[4];
    {
        const float* xrow = x + (rowBase + wid * 32 + col) * VQ_D;
#pragma unroll
        for (int s = 0; s < 4; ++s) {
            const float* xp = xrow + s * 16 + kg * 8;
            f32x4 v0 = *reinterpret_cast<const f32x4*>(xp);
            f32x4 v1 = *reinterpret_cast<const f32x4*>(xp + 4);
            float vv[8] = {v0[0], v0[1], v0[2], v0[3], v1[0], v1[1], v1[2], v1[3]};
#pragma unroll
            for (int j = 0; j < 8; ++j) {
                short h = f2bf_s(vv[j]);
                ah[s][j] = h;
                al[s][j] = f2bf_s(vv[j] - bf2f(h));
            }
        }
    }

    float m1[16], m2[16];
#pragma unroll
    for (int r = 0; r < 16; ++r) { m1[r] = -3.402823466e38f; m2[r] = -3.402823466e38f; }

    __syncthreads();   // wsqm + stage(kt=0) ready (vmcnt drained)

#pragma unroll 1
    for (int kt = 0; kt < VQ_K / 64; ++kt) {
        const int cur = kt & 1;
        // issue next tile's async stage (overwrites cur^1: its readers all
        // passed the previous end-of-iter barrier)
        if (kt < VQ_K / 64 - 1) {
            const short* gn = wS + (size_t)(kt + 1) * 8192 + wid * 1024;
#pragma unroll
            for (int i = 0; i < 2; ++i)
                stage16(gn + i * 512 + lane * 8, &bS[cur ^ 1][wid * 1024 + i * 512]);
        }
#pragma unroll
        for (int h = 0; h < 2; ++h) {
            const int   pk5 = kt * 2 + h;                    // 5-bit scan-local id
            const float wm  = wsqm[kt * 64 + h * 32 + col];  // lane-col bias
            f32x16 acc;
#pragma unroll
            for (int r = 0; r < 16; ++r) acc[r] = wm;
            const short* hb = &bS[cur][h * 4096] + lane * 8;
#pragma unroll
            for (int s = 0; s < 4; ++s) {
                short8_t bh = *reinterpret_cast<const short8_t*>(hb + s * 1024);        // ds_read_b128
                short8_t bl = *reinterpret_cast<const short8_t*>(hb + s * 1024 + 512);
                acc = __builtin_amdgcn_mfma_f32_32x32x16_bf16(ah[s], bh, acc, 0, 0, 0);
                acc = __builtin_amdgcn_mfma_f32_32x32x16_bf16(al[s], bh, acc, 0, 0, 0);
                acc = __builtin_amdgcn_mfma_f32_32x32x16_bf16(ah[s], bl, acc, 0, 0, 0);
            }
#pragma unroll
            for (int r = 0; r < 16; ++r) {
                // pack 5 id bits: 1x v_and_or_b32
                float sp = __int_as_float((__float_as_int(acc[r]) & IMASK) | pk5);
                // m2' = median(sp, m1, m2) since m1>=m2; m1' = max
                m2[r] = __builtin_amdgcn_fmed3f(sp, m1[r], m2[r]);
                m1[r] = fmaxf(m1[r], sp);
            }
        }
        __syncthreads();  // all waves done reading bS[cur]; stage(kt+1) drained
    }

    // ---- cross-lane top-2 merge over the 32 code columns (masks 1..16 stay
    //      within the lane's kg half); index rebuilt from (pk5, own col)
#pragma unroll
    for (int r = 0; r < 16; ++r) {
        float a1 = m1[r]; float a2 = m2[r];
        int   pk = __float_as_int(a1) & 31;
        int   ai = ((pk >> 1) << 6) | ((pk & 1) << 5) | col;
#pragma unroll
        for (int mask = 1; mask < 32; mask <<= 1) {
            float b1 = __shfl_xor(a1, mask, 64);
            int   bi = __shfl_xor(ai, mask, 64);
            float b2 = __shfl_xor(a2, mask, 64);
            float n2 = fmaxf(fmaxf(a2, b2), fminf(a1, b1));
            if (b1 > a1) { a1 = b1; ai = bi; }
            a2 = n2;
        }
        if (col == 0) {
            int row = wid * 32 + (r & 3) + 8 * (r >> 2) + 4 * kg;
            idxL[row] = ai;
            float q1 = __int_as_float(__float_as_int(a1) & IMASK);
            float q2 = __int_as_float(__float_as_int(a2) & IMASK);
            gapL[row] = 2.0f * (q1 - q2);    // distance-space gap (de-packed)
        }
    }
    __syncthreads();

    // ---- outputs
    if (t < ROWS_PER_BLOCK) {
        iout[rowBase + t] = (float)idxL[t];
        if (gapL[t] < EPS) {
            int pos = atomicAdd(counter, 1);
            if (pos < cap) list[pos] = (int)(rowBase + t);
        }
    }
#pragma unroll
    for (int it = 0; it < 8; ++it) {
        int cid = it * 512 + t;            // 4096 float4 chunks
        int row = cid >> 4, seg = cid & 15;
        int idx = idxL[row];
        reinterpret_cast<f32x4*>(qout + (rowBase + row) * VQ_D)[seg] =
            reinterpret_cast<const f32x4*>(w + (size_t)idx * VQ_D)[seg];
    }
}

// ---------------- kernel 2: exact fp32 re-solve, 4 rows per chunk (codes-outer)
// Round-2 structure verbatim (known-good: no spill; FIX_ROWS=16 spilled, r3).
__global__ __launch_bounds__(256) void vq_fix_kernel(
    const float* __restrict__ x, const float* __restrict__ w,
    const float* __restrict__ wsq_g,
    const int* __restrict__ counter, const int* __restrict__ list, int cap,
    float* __restrict__ qout, float* __restrict__ iout, int N) {

    __shared__ __align__(16) float xs[4][VQ_D];
    __shared__ float xsqS[4];
    __shared__ float rvS[4][4];       // [wave][row]
    __shared__ int   riS[4][4];
    __shared__ int   rowsS[4];
    __shared__ int   bestS[4];

    const int t = threadIdx.x;
    const int wid = t >> 6, lane = t & 63;
    int cnt = *counter;
    bool ovf = cnt > cap;
    int nwork = ovf ? N : cnt;

    for (int base = blockIdx.x * 4; base < nwork; base += gridDim.x * 4) {
        if (t < 4) {
            int gi = base + t;
            rowsS[t] = (gi < nwork) ? (ovf ? gi : list[gi]) : -1;
        }
        __syncthreads();
        if (t < 64) {
            int j = t >> 4, seg = t & 15;
            int row = rowsS[j];
            if (row >= 0)
                reinterpret_cast<f32x4*>(xs[j])[seg] =
                    reinterpret_cast<const f32x4*>(x + (size_t)row * VQ_D)[seg];
        }
        __syncthreads();
        if (t < 4 && rowsS[t] >= 0) {
            float sx = 0.f, sy = 0.f, sz = 0.f, sw = 0.f;
#pragma unroll
            for (int j16 = 0; j16 < 16; ++j16) {
                f32x4 v = reinterpret_cast<const f32x4*>(xs[t])[j16];
                sx = fmaf(v[0], v[0], sx); sy = fmaf(v[1], v[1], sy);
                sz = fmaf(v[2], v[2], sz); sw = fmaf(v[3], v[3], sw);
            }
            xsqS[t] = (sx + sy) + (sz + sw);
        }
        __syncthreads();

        float bm[4]; int bk[4];
#pragma unroll
        for (int j = 0; j < 4; ++j) { bm[j] = 3.402823466e38f; bk[j] = 0x7fffffff; }

        for (int p = 0; p < 4; ++p) {
            int k = p * 256 + t;                   // ascending per thread
            f32x4 wv[16];
#pragma unroll
            for (int s16 = 0; s16 < 16; ++s16)
                wv[s16] = reinterpret_cast<const f32x4*>(w + (size_t)k * VQ_D)[s16];
            float wsqk = wsq_g[k];
#pragma unroll
            for (int j = 0; j < 4; ++j) {
                float ax = 0.f, ay = 0.f, az = 0.f, aw = 0.f;
#pragma unroll
                for (int s16 = 0; s16 < 16; ++s16) {
                    f32x4 xv = reinterpret_cast<const f32x4*>(xs[j])[s16];  // broadcast
                    ax = fmaf(xv[0], wv[s16][0], ax); ay = fmaf(xv[1], wv[s16][1], ay);
                    az = fmaf(xv[2], wv[s16][2], az); aw = fmaf(xv[3], wv[s16][3], aw);
                }
                float dot = (ax + ay) + (az + aw);
                float s = (xsqS[j] - 2.0f * dot) + wsqk;   // bit-identical round-2 chain
                if (s < bm[j]) { bm[j] = s; bk[j] = k; }
            }
        }

        // per-row reduce: wave shfl_xor lex-min, then cross-wave merge in LDS
#pragma unroll
        for (int j = 0; j < 4; ++j) {
            float v = bm[j]; int kk = bk[j];
#pragma unroll
            for (int off = 32; off > 0; off >>= 1) {
                float ov = __shfl_xor(v, off, 64);
                int   oi = __shfl_xor(kk, off, 64);
                if (ov < v || (ov == v && oi < kk)) { v = ov; kk = oi; }
            }
            if (lane == 0) { rvS[wid][j] = v; riS[wid][j] = kk; }
        }
        __syncthreads();
        if (t < 4) {
            int row = rowsS[t];
            if (row >= 0) {
                float v = rvS[0][t]; int kk = riS[0][t];
#pragma unroll
                for (int u = 1; u < 4; ++u) {
                    float ov = rvS[u][t]; int oi = riS[u][t];
                    if (ov < v || (ov == v && oi < kk)) { v = ov; kk = oi; }
                }
                iout[row] = (float)kk;
                bestS[t] = kk;
            }
        }
        __syncthreads();
        {
            int j = wid;                       // wave j copies row j
            int row = rowsS[j];
            if (row >= 0)
                qout[(size_t)row * VQ_D + lane] = w[(size_t)bestS[j] * VQ_D + lane];
        }
        __syncthreads();   // xs/rowsS/bestS reuse
    }
}

extern "C" void kernel_launch(void* const* d_in, const int* in_sizes, int n_in,
                              void* d_out, int out_size, void* d_ws, size_t ws_size,
                              hipStream_t stream) {
    const float* x = (const float*)d_in[0];
    const float* w = (const float*)d_in[1];
    const int N = in_sizes[0] / VQ_D;      // 262144

    float* qout = (float*)d_out;
    float* iout = qout + (size_t)N * VQ_D;

    // workspace layout
    char* ws = (char*)d_ws;
    short* wS      = (short*)(ws);                   // 256 KiB swizzled hi/lo codebook
    float* wsq_g   = (float*)(ws + 262144);          // 4 KiB exact ||w||^2
    float* wsqm_g  = (float*)(ws + 266240);          // 4 KiB  -||w||^2/2 (MFMA bias)
    int*   counter = (int*)(ws + 270336);            // 4 B
    int*   list    = (int*)(ws + 270340);
    long long capLL = ((long long)ws_size - 270340) / 4;
    int cap = capLL < 0 ? 0 : (capLL > N ? N : (int)capLL);

    vq_prep_kernel<<<VQ_K / 256, 256, 0, stream>>>(w, wS, wsq_g, wsqm_g, counter);
    vq_main_kernel<<<N / ROWS_PER_BLOCK, 512, 0, stream>>>(
        x, wS, wsqm_g, w, qout, iout, counter, list, cap);
    vq_fix_kernel<<<512, 256, 0, stream>>>(x, w, wsq_g, counter, list, cap, qout, iout, N);
}

// Round 10
// 249.853 us; speedup vs baseline: 1.0149x; 1.0149x over previous
//
#include <hip/hip_runtime.h>
#include <hip/hip_bf16.h>

#define VQ_D   64
#define VQ_K   1024
#define ROWS_PER_BLOCK 256           // 4 waves x 64 rows (rt=4: best-main structure, r7)
#define EPS    0.02f                 // 0.015 bf16-split margin + 0.005 for 6-bit pack
                                     // (validated rounds 4-9: absmax 0.0, small flagged set)

typedef __attribute__((ext_vector_type(8))) short short8_t;
typedef __attribute__((ext_vector_type(4))) float f32x4;

static __device__ __forceinline__ short f2bf_s(float f) {
    __hip_bfloat16 b = __float2bfloat16(f);
    short s; __builtin_memcpy(&s, &b, 2); return s;
}
static __device__ __forceinline__ float bf2f(short s) {
    __hip_bfloat16 b; __builtin_memcpy(&b, &s, 2); return __bfloat162float(b);
}

// async 16B/lane global->LDS copy (gfx950). lds base is wave-uniform; HW
// writes base + lane*16. Global src is per-lane.
typedef const __attribute__((address_space(1))) unsigned int* gas_t;
typedef       __attribute__((address_space(3))) unsigned int* las_t;
static __device__ __forceinline__ void stage16(const void* g, void* l) {
    __builtin_amdgcn_global_load_lds((gas_t)g, (las_t)l, 16, 0, 0);
}

// ---------------- kernel 0: swizzle w into per-lane MFMA fragment order + wsq
// wS layout: chunk T = 16 codes (T = c>>4, 64 chunks) = 2048 shorts:
//   sub 0: hi K-half 0, sub 1: hi K-half 1, sub 2: lo K-half 0, sub 3: lo K-half 1
//   within sub: slot (q*16 + l) * 8 shorts  (q = k-quad, l = code mod 16)
// Grid widened 4->8 blocks (128 thr): prep occupied only 4 CUs before.
__global__ __launch_bounds__(128) void vq_prep_kernel(
    const float* __restrict__ w, short* __restrict__ wS,
    float* __restrict__ wsq_g, float* __restrict__ wsqm_g,
    int* __restrict__ counter) {
    const int c = blockIdx.x * 128 + threadIdx.x;   // code id; grid = K/128
    if (c == 0) *counter = 0;
    if (c >= VQ_K) return;
    const int T = c >> 4, l = c & 15;
    short* tbase = wS + (size_t)T * 2048;
    float sx = 0.f, sy = 0.f, sz = 0.f, sw = 0.f;
#pragma unroll
    for (int b = 0; b < 2; ++b)
#pragma unroll
        for (int q = 0; q < 4; ++q) {
            const float* src = w + (size_t)c * VQ_D + b * 32 + q * 8;
            f32x4 v0 = *reinterpret_cast<const f32x4*>(src);
            f32x4 v1 = *reinterpret_cast<const f32x4*>(src + 4);
            float vv[8] = {v0[0], v0[1], v0[2], v0[3], v1[0], v1[1], v1[2], v1[3]};
            short8_t hs, ls;
#pragma unroll
            for (int j = 0; j < 8; ++j) {
                short h = f2bf_s(vv[j]);
                hs[j] = h;
                ls[j] = f2bf_s(vv[j] - bf2f(h));
            }
            *reinterpret_cast<short8_t*>(tbase + b * 512 + (q * 16 + l) * 8) = hs;
            *reinterpret_cast<short8_t*>(tbase + 1024 + b * 512 + (q * 16 + l) * 8) = ls;
            // wsq in EXACT round-2 partial order (f32x4 ascending, 4 chains)
            sx = fmaf(v0[0], v0[0], sx); sy = fmaf(v0[1], v0[1], sy);
            sz = fmaf(v0[2], v0[2], sz); sw = fmaf(v0[3], v0[3], sw);
            sx = fmaf(v1[0], v1[0], sx); sy = fmaf(v1[1], v1[1], sy);
            sz = fmaf(v1[2], v1[2], sz); sw = fmaf(v1[3], v1[3], sw);
        }
    float s = (sx + sy) + (sz + sw);
    wsq_g[c]  = s;            // exact, for fix kernel
    wsqm_g[c] = -0.5f * s;    // MFMA C-bias: argmax(dot - wsq/2) == argmin(wsq - 2dot)
}

// ---------------- kernel 1: MFMA scores, 6-bit-packed top-2, LDS-staged B
// r7 base (best main: 117us) + unroll 2 on kt (never measured WITH staging;
// in the unstaged variant unroll width was worth +-30us, r5/r6).
__global__ __launch_bounds__(256, 3) void vq_main_kernel(
    const float* __restrict__ x, const short* __restrict__ wS,
    const float* __restrict__ wsqm_g, const float* __restrict__ w,
    float* __restrict__ qout, float* __restrict__ iout,
    int* __restrict__ counter, int* __restrict__ list, int cap) {

    __shared__ short bS[2][8192];         // 32 KB: double-buffered 16KB kt-tile
    __shared__ float wsqm[VQ_K];          // 4 KB
    __shared__ int   idxL[ROWS_PER_BLOCK];
    __shared__ float gapL[ROWS_PER_BLOCK];

    const int t    = threadIdx.x;
    const int wid  = t >> 6;
    const int lane = t & 63;
    const int quad = lane >> 4;
    const int ln15 = lane & 15;
    const long long rowBase = (long long)blockIdx.x * ROWS_PER_BLOCK;
    const int IMASK = (int)0xFFFFFFC0u;   // clears 6 code bits

    // ---- stage wsqm (block-shared)
#pragma unroll
    for (int i = 0; i < 4; ++i) wsqm[i * 256 + t] = wsqm_g[i * 256 + t];

    // ---- prologue: async-stage kt=0 into buf 0 (wave wid -> ct=wid quadrant)
    {
        const short* g0 = wS + (size_t)wid * 2048;
#pragma unroll
        for (int i = 0; i < 4; ++i)
            stage16(g0 + i * 512 + lane * 8, &bS[0][wid * 2048 + i * 512]);
    }

    // ---- A fragments straight from global x (hi/lo bf16 split)
    short8_t ah[4][2], al[4][2];
#pragma unroll
    for (int rt = 0; rt < 4; ++rt)
#pragma unroll
        for (int ks = 0; ks < 2; ++ks) {
            const float* xp = x + (rowBase + wid * 64 + rt * 16 + ln15) * VQ_D + ks * 32 + quad * 8;
            f32x4 v0 = *reinterpret_cast<const f32x4*>(xp);
            f32x4 v1 = *reinterpret_cast<const f32x4*>(xp + 4);
            float vv[8] = {v0[0], v0[1], v0[2], v0[3], v1[0], v1[1], v1[2], v1[3]};
#pragma unroll
            for (int j = 0; j < 8; ++j) {
                short h = f2bf_s(vv[j]);
                ah[rt][ks][j] = h;
                al[rt][ks][j] = f2bf_s(vv[j] - bf2f(h));
            }
        }

    float m1[4][4], m2[4][4];
#pragma unroll
    for (int rt = 0; rt < 4; ++rt)
#pragma unroll
        for (int r = 0; r < 4; ++r) {
            m1[rt][r] = -3.402823466e38f; m2[rt][r] = -3.402823466e38f;
        }

    __syncthreads();   // wsqm + stage(kt=0) ready (compiler drains vmcnt here)

    const int laneoff = lane * 8;     // shorts
#pragma unroll 2
    for (int kt = 0; kt < VQ_K / 64; ++kt) {
        const int cur = kt & 1;
        // issue next tile's async stage; overwrites cur^1, whose readers all
        // passed the previous end-of-iter barrier
        if (kt < VQ_K / 64 - 1) {
            const short* gn = wS + (size_t)(kt + 1) * 8192 + wid * 2048;
#pragma unroll
            for (int i = 0; i < 4; ++i)
                stage16(gn + i * 512 + lane * 8, &bS[cur ^ 1][wid * 2048 + i * 512]);
        }
#pragma unroll
        for (int ct = 0; ct < 4; ++ct) {
            const short* cb = &bS[cur][ct * 2048] + laneoff;
            short8_t bh0 = *reinterpret_cast<const short8_t*>(cb);          // ds_read_b128
            short8_t bh1 = *reinterpret_cast<const short8_t*>(cb + 512);
            short8_t bl0 = *reinterpret_cast<const short8_t*>(cb + 1024);
            short8_t bl1 = *reinterpret_cast<const short8_t*>(cb + 1536);
            const int   code6 = kt * 4 + ct;      // loop-constant, 0..63
            const int   kc = code6 * 16 + ln15;
            const float wm = wsqm[kc];     // 16 banks, 4-way broadcast: conflict-free
            const f32x4 winit = {wm, wm, wm, wm};   // shared C-bias for all rt chains
#pragma unroll
            for (int rt = 0; rt < 4; ++rt) {
                f32x4 acc;
                acc = __builtin_amdgcn_mfma_f32_16x16x32_bf16(ah[rt][0], bh0, winit, 0, 0, 0);
                acc = __builtin_amdgcn_mfma_f32_16x16x32_bf16(al[rt][0], bh0, acc, 0, 0, 0);
                acc = __builtin_amdgcn_mfma_f32_16x16x32_bf16(ah[rt][0], bl0, acc, 0, 0, 0);
                acc = __builtin_amdgcn_mfma_f32_16x16x32_bf16(ah[rt][1], bh1, acc, 0, 0, 0);
                acc = __builtin_amdgcn_mfma_f32_16x16x32_bf16(al[rt][1], bh1, acc, 0, 0, 0);
                acc = __builtin_amdgcn_mfma_f32_16x16x32_bf16(ah[rt][1], bl1, acc, 0, 0, 0);
#pragma unroll
                for (int r = 0; r < 4; ++r) {
                    // pack 6 code bits: 1x v_and_or_b32
                    float sp = __int_as_float((__float_as_int(acc[r]) & IMASK) | code6);
                    // m2' = median(sp, m1, m2) since m1>=m2; m1' = max
                    m2[rt][r] = __builtin_amdgcn_fmed3f(sp, m1[rt][r], m2[rt][r]);
                    m1[rt][r] = fmaxf(m1[rt][r], sp);
                }
            }
        }
        __syncthreads();  // all waves done reading bS[cur]; stage(kt+1) drained
    }

    // ---- cross-lane top-2 merge within each 16-lane group; index rebuilt
    //      from (code6, own ln15) then shuffled alongside the value
#pragma unroll
    for (int rt = 0; rt < 4; ++rt)
#pragma unroll
        for (int r = 0; r < 4; ++r) {
            float a1 = m1[rt][r]; float a2 = m2[rt][r];
            int   ai = ((__float_as_int(a1) & 63) << 4) | ln15;
#pragma unroll
            for (int mask = 1; mask < 16; mask <<= 1) {
                float b1 = __shfl_xor(a1, mask, 64);
                int   bi = __shfl_xor(ai, mask, 64);
                float b2 = __shfl_xor(a2, mask, 64);
                float n2 = fmaxf(fmaxf(a2, b2), fminf(a1, b1));
                if (b1 > a1) { a1 = b1; ai = bi; }
                a2 = n2;
            }
            if (ln15 == 0) {
                int row = wid * 64 + rt * 16 + quad * 4 + r;
                idxL[row] = ai;
                float q1 = __int_as_float(__float_as_int(a1) & IMASK);
                float q2 = __int_as_float(__float_as_int(a2) & IMASK);
                gapL[row] = 2.0f * (q1 - q2);    // distance-space gap (de-packed)
            }
        }
    __syncthreads();

    // ---- outputs
    iout[rowBase + t] = (float)idxL[t];
    if (gapL[t] < EPS) {
        int pos = atomicAdd(counter, 1);
        if (pos < cap) list[pos] = (int)(rowBase + t);
    }
#pragma unroll
    for (int it = 0; it < 16; ++it) {
        int cid = it * 256 + t;            // 4096 float4 chunks
        int row = cid >> 4, seg = cid & 15;
        int idx = idxL[row];
        reinterpret_cast<f32x4*>(qout + (rowBase + row) * VQ_D)[seg] =
            reinterpret_cast<const f32x4*>(w + (size_t)idx * VQ_D)[seg];
    }
}

// ---------------- kernel 2: exact fp32 re-solve, 4 rows per chunk (codes-outer)
// Round-2 structure verbatim (known-good: no spill; FIX_ROWS=16 spilled, r3).
__global__ __launch_bounds__(256) void vq_fix_kernel(
    const float* __restrict__ x, const float* __restrict__ w,
    const float* __restrict__ wsq_g,
    const int* __restrict__ counter, const int* __restrict__ list, int cap,
    float* __restrict__ qout, float* __restrict__ iout, int N) {

    __shared__ __align__(16) float xs[4][VQ_D];
    __shared__ float xsqS[4];
    __shared__ float rvS[4][4];       // [wave][row]
    __shared__ int   riS[4][4];
    __shared__ int   rowsS[4];
    __shared__ int   bestS[4];

    const int t = threadIdx.x;
    const int wid = t >> 6, lane = t & 63;
    int cnt = *counter;
    bool ovf = cnt > cap;
    int nwork = ovf ? N : cnt;

    for (int base = blockIdx.x * 4; base < nwork; base += gridDim.x * 4) {
        if (t < 4) {
            int gi = base + t;
            rowsS[t] = (gi < nwork) ? (ovf ? gi : list[gi]) : -1;
        }
        __syncthreads();
        if (t < 64) {
            int j = t >> 4, seg = t & 15;
            int row = rowsS[j];
            if (row >= 0)
                reinterpret_cast<f32x4*>(xs[j])[seg] =
                    reinterpret_cast<const f32x4*>(x + (size_t)row * VQ_D)[seg];
        }
        __syncthreads();
        if (t < 4 && rowsS[t] >= 0) {
            float sx = 0.f, sy = 0.f, sz = 0.f, sw = 0.f;
#pragma unroll
            for (int j16 = 0; j16 < 16; ++j16) {
                f32x4 v = reinterpret_cast<const f32x4*>(xs[t])[j16];
                sx = fmaf(v[0], v[0], sx); sy = fmaf(v[1], v[1], sy);
                sz = fmaf(v[2], v[2], sz); sw = fmaf(v[3], v[3], sw);
            }
            xsqS[t] = (sx + sy) + (sz + sw);
        }
        __syncthreads();

        float bm[4]; int bk[4];
#pragma unroll
        for (int j = 0; j < 4; ++j) { bm[j] = 3.402823466e38f; bk[j] = 0x7fffffff; }

        for (int p = 0; p < 4; ++p) {
            int k = p * 256 + t;                   // ascending per thread
            f32x4 wv[16];
#pragma unroll
            for (int s16 = 0; s16 < 16; ++s16)
                wv[s16] = reinterpret_cast<const f32x4*>(w + (size_t)k * VQ_D)[s16];
            float wsqk = wsq_g[k];
#pragma unroll
            for (int j = 0; j < 4; ++j) {
                float ax = 0.f, ay = 0.f, az = 0.f, aw = 0.f;
#pragma unroll
                for (int s16 = 0; s16 < 16; ++s16) {
                    f32x4 xv = reinterpret_cast<const f32x4*>(xs[j])[s16];  // broadcast
                    ax = fmaf(xv[0], wv[s16][0], ax); ay = fmaf(xv[1], wv[s16][1], ay);
                    az = fmaf(xv[2], wv[s16][2], az); aw = fmaf(xv[3], wv[s16][3], aw);
                }
                float dot = (ax + ay) + (az + aw);
                float s = (xsqS[j] - 2.0f * dot) + wsqk;   // bit-identical round-2 chain
                if (s < bm[j]) { bm[j] = s; bk[j] = k; }
            }
        }

        // per-row reduce: wave shfl_xor lex-min, then cross-wave merge in LDS
#pragma unroll
        for (int j = 0; j < 4; ++j) {
            float v = bm[j]; int kk = bk[j];
#pragma unroll
            for (int off = 32; off > 0; off >>= 1) {
                float ov = __shfl_xor(v, off, 64);
                int   oi = __shfl_xor(kk, off, 64);
                if (ov < v || (ov == v && oi < kk)) { v = ov; kk = oi; }
            }
            if (lane == 0) { rvS[wid][j] = v; riS[wid][j] = kk; }
        }
        __syncthreads();
        if (t < 4) {
            int row = rowsS[t];
            if (row >= 0) {
                float v = rvS[0][t]; int kk = riS[0][t];
#pragma unroll
                for (int u = 1; u < 4; ++u) {
                    float ov = rvS[u][t]; int oi = riS[u][t];
                    if (ov < v || (ov == v && oi < kk)) { v = ov; kk = oi; }
                }
                iout[row] = (float)kk;
                bestS[t] = kk;
            }
        }
        __syncthreads();
        {
            int j = wid;                       // wave j copies row j
            int row = rowsS[j];
            if (row >= 0)
                qout[(size_t)row * VQ_D + lane] = w[(size_t)bestS[j] * VQ_D + lane];
        }
        __syncthreads();   // xs/rowsS/bestS reuse
    }
}

extern "C" void kernel_launch(void* const* d_in, const int* in_sizes, int n_in,
                              void* d_out, int out_size, void* d_ws, size_t ws_size,
                              hipStream_t stream) {
    const float* x = (const float*)d_in[0];
    const float* w = (const float*)d_in[1];
    const int N = in_sizes[0] / VQ_D;      // 262144

    float* qout = (float*)d_out;
    float* iout = qout + (size_t)N * VQ_D;

    // workspace layout
    char* ws = (char*)d_ws;
    short* wS      = (short*)(ws);                   // 256 KiB swizzled hi/lo codebook
    float* wsq_g   = (float*)(ws + 262144);          // 4 KiB exact ||w||^2
    float* wsqm_g  = (float*)(ws + 266240);          // 4 KiB  -||w||^2/2 (MFMA bias)
    int*   counter = (int*)(ws + 270336);            // 4 B
    int*   list    = (int*)(ws + 270340);
    long long capLL = ((long long)ws_size - 270340) / 4;
    int cap = capLL < 0 ? 0 : (capLL > N ? N : (int)capLL);

    vq_prep_kernel<<<VQ_K / 128, 128, 0, stream>>>(w, wS, wsq_g, wsqm_g, counter);
    vq_main_kernel<<<N / ROWS_PER_BLOCK, 256, 0, stream>>>(
        x, wS, wsqm_g, w, qout, iout, counter, list, cap);
    vq_fix_kernel<<<512, 256, 0, stream>>>(x, w, wsq_g, counter, list, cap, qout, iout, N);
}

// Round 11
// 236.289 us; speedup vs baseline: 1.0731x; 1.0574x over previous
//
#include <hip/hip_runtime.h>
#include <hip/hip_bf16.h>

#define VQ_D   64
#define VQ_K   1024
#define ROWS_PER_BLOCK 256           // 8 waves x 32 rows (rt=2), LDS-staged B (r8 = best total)
#define EPS    0.02f                 // 0.015 bf16-split margin + 0.005 for 6-bit pack
                                     // (validated rounds 4-10: absmax 0.0, small flagged set)

typedef __attribute__((ext_vector_type(8))) short short8_t;
typedef __attribute__((ext_vector_type(4))) float f32x4;

static __device__ __forceinline__ short f2bf_s(float f) {
    __hip_bfloat16 b = __float2bfloat16(f);
    short s; __builtin_memcpy(&s, &b, 2); return s;
}
static __device__ __forceinline__ float bf2f(short s) {
    __hip_bfloat16 b; __builtin_memcpy(&b, &s, 2); return __bfloat162float(b);
}

// async 16B/lane global->LDS copy (gfx950). lds base is wave-uniform; HW
// writes base + lane*16. Global src is per-lane.
typedef const __attribute__((address_space(1))) unsigned int* gas_t;
typedef       __attribute__((address_space(3))) unsigned int* las_t;
static __device__ __forceinline__ void stage16(const void* g, void* l) {
    __builtin_amdgcn_global_load_lds((gas_t)g, (las_t)l, 16, 0, 0);
}

// ---------------- kernel 0: swizzle w into per-lane MFMA fragment order + wsq
// wS layout: chunk T = 16 codes (T = c>>4, 64 chunks) = 2048 shorts:
//   sub 0: hi K-half 0, sub 1: hi K-half 1, sub 2: lo K-half 0, sub 3: lo K-half 1
//   within sub: slot (q*16 + l) * 8 shorts  (q = k-quad, l = code mod 16)
// 8 blocks x 128 threads (r10 delta, benign): halves serial prep latency.
__global__ __launch_bounds__(128) void vq_prep_kernel(
    const float* __restrict__ w, short* __restrict__ wS,
    float* __restrict__ wsq_g, float* __restrict__ wsqm_g,
    int* __restrict__ counter) {
    const int c = blockIdx.x * 128 + threadIdx.x;   // code id; grid = K/128
    if (c == 0) *counter = 0;
    if (c >= VQ_K) return;
    const int T = c >> 4, l = c & 15;
    short* tbase = wS + (size_t)T * 2048;
    float sx = 0.f, sy = 0.f, sz = 0.f, sw = 0.f;
#pragma unroll
    for (int b = 0; b < 2; ++b)
#pragma unroll
        for (int q = 0; q < 4; ++q) {
            const float* src = w + (size_t)c * VQ_D + b * 32 + q * 8;
            f32x4 v0 = *reinterpret_cast<const f32x4*>(src);
            f32x4 v1 = *reinterpret_cast<const f32x4*>(src + 4);
            float vv[8] = {v0[0], v0[1], v0[2], v0[3], v1[0], v1[1], v1[2], v1[3]};
            short8_t hs, ls;
#pragma unroll
            for (int j = 0; j < 8; ++j) {
                short h = f2bf_s(vv[j]);
                hs[j] = h;
                ls[j] = f2bf_s(vv[j] - bf2f(h));
            }
            *reinterpret_cast<short8_t*>(tbase + b * 512 + (q * 16 + l) * 8) = hs;
            *reinterpret_cast<short8_t*>(tbase + 1024 + b * 512 + (q * 16 + l) * 8) = ls;
            // wsq in EXACT round-2 partial order (f32x4 ascending, 4 chains)
            sx = fmaf(v0[0], v0[0], sx); sy = fmaf(v0[1], v0[1], sy);
            sz = fmaf(v0[2], v0[2], sz); sw = fmaf(v0[3], v0[3], sw);
            sx = fmaf(v1[0], v1[0], sx); sy = fmaf(v1[1], v1[1], sy);
            sz = fmaf(v1[2], v1[2], sz); sw = fmaf(v1[3], v1[3], sw);
        }
    float s = (sx + sy) + (sz + sw);
    wsq_g[c]  = s;            // exact, for fix kernel
    wsqm_g[c] = -0.5f * s;    // MFMA C-bias: argmax(dot - wsq/2) == argmin(wsq - 2dot)
}

// ---------------- kernel 1: MFMA scores, 6-bit-packed top-2, LDS-staged B
// r8 verbatim (best total 236.7us). 8 waves x 32 rows (rt=2); combined
// VGPR+AGPR ~95 fits the 128-reg bucket -> 38% occupancy; B staged via
// global_load_lds double-buffer (conflict-free); kt loop unroll 1 (unroll 2
// + staging spills: r10, FETCH/WRITE +40MB scratch).
__global__ __launch_bounds__(512, 2) void vq_main_kernel(
    const float* __restrict__ x, const short* __restrict__ wS,
    const float* __restrict__ wsqm_g, const float* __restrict__ w,
    float* __restrict__ qout, float* __restrict__ iout,
    int* __restrict__ counter, int* __restrict__ list, int cap) {

    __shared__ short bS[2][8192];         // 32 KB: double-buffered 16KB kt-tile
    __shared__ float wsqm[VQ_K];          // 4 KB
    __shared__ int   idxL[ROWS_PER_BLOCK];
    __shared__ float gapL[ROWS_PER_BLOCK];

    const int t    = threadIdx.x;         // 0..511
    const int wid  = t >> 6;              // 0..7
    const int lane = t & 63;
    const int quad = lane >> 4;
    const int ln15 = lane & 15;
    const long long rowBase = (long long)blockIdx.x * ROWS_PER_BLOCK;
    const int IMASK = (int)0xFFFFFFC0u;   // clears 6 code bits

    // ---- stage wsqm (block-shared)
#pragma unroll
    for (int i = 0; i < 2; ++i) wsqm[i * 512 + t] = wsqm_g[i * 512 + t];

    // ---- prologue: async-stage kt=0 into buf 0
    // wave w owns quadrant ct=w>>1, half (w&1): 2x stage16 (1KB each)
    const int sOff = (wid >> 1) * 2048 + (wid & 1) * 1024;   // shorts
    {
        const short* g0 = wS + sOff;
#pragma unroll
        for (int i = 0; i < 2; ++i)
            stage16(g0 + i * 512 + lane * 8, &bS[0][sOff + i * 512]);
    }

    // ---- A fragments straight from global x (hi/lo bf16 split)
    short8_t ah[2][2], al[2][2];
#pragma unroll
    for (int rt = 0; rt < 2; ++rt)
#pragma unroll
        for (int ks = 0; ks < 2; ++ks) {
            const float* xp = x + (rowBase + wid * 32 + rt * 16 + ln15) * VQ_D + ks * 32 + quad * 8;
            f32x4 v0 = *reinterpret_cast<const f32x4*>(xp);
            f32x4 v1 = *reinterpret_cast<const f32x4*>(xp + 4);
            float vv[8] = {v0[0], v0[1], v0[2], v0[3], v1[0], v1[1], v1[2], v1[3]};
#pragma unroll
            for (int j = 0; j < 8; ++j) {
                short h = f2bf_s(vv[j]);
                ah[rt][ks][j] = h;
                al[rt][ks][j] = f2bf_s(vv[j] - bf2f(h));
            }
        }

    float m1[2][4], m2[2][4];
#pragma unroll
    for (int rt = 0; rt < 2; ++rt)
#pragma unroll
        for (int r = 0; r < 4; ++r) {
            m1[rt][r] = -3.402823466e38f; m2[rt][r] = -3.402823466e38f;
        }

    __syncthreads();   // wsqm + stage(kt=0) ready (compiler drains vmcnt here)

    const int laneoff = lane * 8;     // shorts
#pragma unroll 1
    for (int kt = 0; kt < VQ_K / 64; ++kt) {
        const int cur = kt & 1;
        // issue next tile's async stage; overwrites cur^1, whose readers all
        // passed the previous end-of-iter barrier
        if (kt < VQ_K / 64 - 1) {
            const short* gn = wS + (size_t)(kt + 1) * 8192 + sOff;
#pragma unroll
            for (int i = 0; i < 2; ++i)
                stage16(gn + i * 512 + lane * 8, &bS[cur ^ 1][sOff + i * 512]);
        }
#pragma unroll
        for (int ct = 0; ct < 4; ++ct) {
            const short* cb = &bS[cur][ct * 2048] + laneoff;
            short8_t bh0 = *reinterpret_cast<const short8_t*>(cb);          // ds_read_b128
            short8_t bh1 = *reinterpret_cast<const short8_t*>(cb + 512);
            short8_t bl0 = *reinterpret_cast<const short8_t*>(cb + 1024);
            short8_t bl1 = *reinterpret_cast<const short8_t*>(cb + 1536);
            const int   code6 = kt * 4 + ct;      // loop-constant, 0..63
            const int   kc = code6 * 16 + ln15;
            const float wm = wsqm[kc];     // 16 banks, 4-way broadcast: conflict-free
            const f32x4 winit = {wm, wm, wm, wm};   // shared C-bias for both rt chains
#pragma unroll
            for (int rt = 0; rt < 2; ++rt) {
                f32x4 acc;
                acc = __builtin_amdgcn_mfma_f32_16x16x32_bf16(ah[rt][0], bh0, winit, 0, 0, 0);
                acc = __builtin_amdgcn_mfma_f32_16x16x32_bf16(al[rt][0], bh0, acc, 0, 0, 0);
                acc = __builtin_amdgcn_mfma_f32_16x16x32_bf16(ah[rt][0], bl0, acc, 0, 0, 0);
                acc = __builtin_amdgcn_mfma_f32_16x16x32_bf16(ah[rt][1], bh1, acc, 0, 0, 0);
                acc = __builtin_amdgcn_mfma_f32_16x16x32_bf16(al[rt][1], bh1, acc, 0, 0, 0);
                acc = __builtin_amdgcn_mfma_f32_16x16x32_bf16(ah[rt][1], bl1, acc, 0, 0, 0);
#pragma unroll
                for (int r = 0; r < 4; ++r) {
                    // pack 6 code bits: 1x v_and_or_b32
                    float sp = __int_as_float((__float_as_int(acc[r]) & IMASK) | code6);
                    // m2' = median(sp, m1, m2) since m1>=m2; m1' = max
                    m2[rt][r] = __builtin_amdgcn_fmed3f(sp, m1[rt][r], m2[rt][r]);
                    m1[rt][r] = fmaxf(m1[rt][r], sp);
                }
            }
        }
        __syncthreads();  // all waves done reading bS[cur]; stage(kt+1) drained
    }

    // ---- cross-lane top-2 merge within each 16-lane group; index rebuilt
    //      from (code6, own ln15) then shuffled alongside the value
#pragma unroll
    for (int rt = 0; rt < 2; ++rt)
#pragma unroll
        for (int r = 0; r < 4; ++r) {
            float a1 = m1[rt][r]; float a2 = m2[rt][r];
            int   ai = ((__float_as_int(a1) & 63) << 4) | ln15;
#pragma unroll
            for (int mask = 1; mask < 16; mask <<= 1) {
                float b1 = __shfl_xor(a1, mask, 64);
                int   bi = __shfl_xor(ai, mask, 64);
                float b2 = __shfl_xor(a2, mask, 64);
                float n2 = fmaxf(fmaxf(a2, b2), fminf(a1, b1));
                if (b1 > a1) { a1 = b1; ai = bi; }
                a2 = n2;
            }
            if (ln15 == 0) {
                int row = wid * 32 + rt * 16 + quad * 4 + r;
                idxL[row] = ai;
                float q1 = __int_as_float(__float_as_int(a1) & IMASK);
                float q2 = __int_as_float(__float_as_int(a2) & IMASK);
                gapL[row] = 2.0f * (q1 - q2);    // distance-space gap (de-packed)
            }
        }
    __syncthreads();

    // ---- outputs
    if (t < ROWS_PER_BLOCK) {
        iout[rowBase + t] = (float)idxL[t];
        if (gapL[t] < EPS) {
            int pos = atomicAdd(counter, 1);
            if (pos < cap) list[pos] = (int)(rowBase + t);
        }
    }
#pragma unroll
    for (int it = 0; it < 8; ++it) {
        int cid = it * 512 + t;            // 4096 float4 chunks
        int row = cid >> 4, seg = cid & 15;
        int idx = idxL[row];
        reinterpret_cast<f32x4*>(qout + (rowBase + row) * VQ_D)[seg] =
            reinterpret_cast<const f32x4*>(w + (size_t)idx * VQ_D)[seg];
    }
}

// ---------------- kernel 2: exact fp32 re-solve, 4 rows per chunk (codes-outer)
// Round-2 structure verbatim (known-good: no spill; FIX_ROWS=16 spilled, r3).
__global__ __launch_bounds__(256) void vq_fix_kernel(
    const float* __restrict__ x, const float* __restrict__ w,
    const float* __restrict__ wsq_g,
    const int* __restrict__ counter, const int* __restrict__ list, int cap,
    float* __restrict__ qout, float* __restrict__ iout, int N) {

    __shared__ __align__(16) float xs[4][VQ_D];
    __shared__ float xsqS[4];
    __shared__ float rvS[4][4];       // [wave][row]
    __shared__ int   riS[4][4];
    __shared__ int   rowsS[4];
    __shared__ int   bestS[4];

    const int t = threadIdx.x;
    const int wid = t >> 6, lane = t & 63;
    int cnt = *counter;
    bool ovf = cnt > cap;
    int nwork = ovf ? N : cnt;

    for (int base = blockIdx.x * 4; base < nwork; base += gridDim.x * 4) {
        if (t < 4) {
            int gi = base + t;
            rowsS[t] = (gi < nwork) ? (ovf ? gi : list[gi]) : -1;
        }
        __syncthreads();
        if (t < 64) {
            int j = t >> 4, seg = t & 15;
            int row = rowsS[j];
            if (row >= 0)
                reinterpret_cast<f32x4*>(xs[j])[seg] =
                    reinterpret_cast<const f32x4*>(x + (size_t)row * VQ_D)[seg];
        }
        __syncthreads();
        if (t < 4 && rowsS[t] >= 0) {
            float sx = 0.f, sy = 0.f, sz = 0.f, sw = 0.f;
#pragma unroll
            for (int j16 = 0; j16 < 16; ++j16) {
                f32x4 v = reinterpret_cast<const f32x4*>(xs[t])[j16];
                sx = fmaf(v[0], v[0], sx); sy = fmaf(v[1], v[1], sy);
                sz = fmaf(v[2], v[2], sz); sw = fmaf(v[3], v[3], sw);
            }
            xsqS[t] = (sx + sy) + (sz + sw);
        }
        __syncthreads();

        float bm[4]; int bk[4];
#pragma unroll
        for (int j = 0; j < 4; ++j) { bm[j] = 3.402823466e38f; bk[j] = 0x7fffffff; }

        for (int p = 0; p < 4; ++p) {
            int k = p * 256 + t;                   // ascending per thread
            f32x4 wv[16];
#pragma unroll
            for (int s16 = 0; s16 < 16; ++s16)
                wv[s16] = reinterpret_cast<const f32x4*>(w + (size_t)k * VQ_D)[s16];
            float wsqk = wsq_g[k];
#pragma unroll
            for (int j = 0; j < 4; ++j) {
                float ax = 0.f, ay = 0.f, az = 0.f, aw = 0.f;
#pragma unroll
                for (int s16 = 0; s16 < 16; ++s16) {
                    f32x4 xv = reinterpret_cast<const f32x4*>(xs[j])[s16];  // broadcast
                    ax = fmaf(xv[0], wv[s16][0], ax); ay = fmaf(xv[1], wv[s16][1], ay);
                    az = fmaf(xv[2], wv[s16][2], az); aw = fmaf(xv[3], wv[s16][3], aw);
                }
                float dot = (ax + ay) + (az + aw);
                float s = (xsqS[j] - 2.0f * dot) + wsqk;   // bit-identical round-2 chain
                if (s < bm[j]) { bm[j] = s; bk[j] = k; }
            }
        }

        // per-row reduce: wave shfl_xor lex-min, then cross-wave merge in LDS
#pragma unroll
        for (int j = 0; j < 4; ++j) {
            float v = bm[j]; int kk = bk[j];
#pragma unroll
            for (int off = 32; off > 0; off >>= 1) {
                float ov = __shfl_xor(v, off, 64);
                int   oi = __shfl_xor(kk, off, 64);
                if (ov < v || (ov == v && oi < kk)) { v = ov; kk = oi; }
            }
            if (lane == 0) { rvS[wid][j] = v; riS[wid][j] = kk; }
        }
        __syncthreads();
        if (t < 4) {
            int row = rowsS[t];
            if (row >= 0) {
                float v = rvS[0][t]; int kk = riS[0][t];
#pragma unroll
                for (int u = 1; u < 4; ++u) {
                    float ov = rvS[u][t]; int oi = riS[u][t];
                    if (ov < v || (ov == v && oi < kk)) { v = ov; kk = oi; }
                }
                iout[row] = (float)kk;
                bestS[t] = kk;
            }
        }
        __syncthreads();
        {
            int j = wid;                       // wave j copies row j
            int row = rowsS[j];
            if (row >= 0)
                qout[(size_t)row * VQ_D + lane] = w[(size_t)bestS[j] * VQ_D + lane];
        }
        __syncthreads();   // xs/rowsS/bestS reuse
    }
}

extern "C" void kernel_launch(void* const* d_in, const int* in_sizes, int n_in,
                              void* d_out, int out_size, void* d_ws, size_t ws_size,
                              hipStream_t stream) {
    const float* x = (const float*)d_in[0];
    const float* w = (const float*)d_in[1];
    const int N = in_sizes[0] / VQ_D;      // 262144

    float* qout = (float*)d_out;
    float* iout = qout + (size_t)N * VQ_D;

    // workspace layout
    char* ws = (char*)d_ws;
    short* wS      = (short*)(ws);                   // 256 KiB swizzled hi/lo codebook
    float* wsq_g   = (float*)(ws + 262144);          // 4 KiB exact ||w||^2
    float* wsqm_g  = (float*)(ws + 266240);          // 4 KiB  -||w||^2/2 (MFMA bias)
    int*   counter = (int*)(ws + 270336);            // 4 B
    int*   list    = (int*)(ws + 270340);
    long long capLL = ((long long)ws_size - 270340) / 4;
    int cap = capLL < 0 ? 0 : (capLL > N ? N : (int)capLL);

    vq_prep_kernel<<<VQ_K / 128, 128, 0, stream>>>(w, wS, wsq_g, wsqm_g, counter);
    vq_main_kernel<<<N / ROWS_PER_BLOCK, 512, 0, stream>>>(
        x, wS, wsqm_g, w, qout, iout, counter, list, cap);
    vq_fix_kernel<<<512, 256, 0, stream>>>(x, w, wsq_g, counter, list, cap, qout, iout, N);
}